// Round 5
// baseline (202.343 us; speedup 1.0000x reference)
//
#include <hip/hip_runtime.h>
#include <hip/hip_bf16.h>

#define L 4096
#define CCH 256
#define NB 4
#define KP 40   // padded LDS row length (32 k + 8 pad) in bf16 elems; 80 B rows
#define GOF 72  // guarded-image front offset (alignment-friendly, >= 65)
#define LOG2E 1.4426950408889634f
#define INVN (1.0f / (NB * (float)L))

typedef __attribute__((ext_vector_type(8))) short short8;
typedef __attribute__((ext_vector_type(4))) float f32x4;
typedef unsigned short ushort_t;

__device__ __forceinline__ unsigned short f2bf(float f) {
    unsigned u = __builtin_bit_cast(unsigned, f);
    u += 0x7FFF + ((u >> 16) & 1);
    return (unsigned short)(u >> 16);
}
__device__ __forceinline__ unsigned pk_bf16(float a, float b) {
    __hip_bfloat162 h = __float22bfloat162_rn(make_float2(a, b));
    unsigned u;
    __builtin_memcpy(&u, &h, 4);
    return u;
}
__device__ __forceinline__ float bflo(unsigned w) {
    return __builtin_bit_cast(float, w << 16);
}
__device__ __forceinline__ float bfhi(unsigned w) {
    return __builtin_bit_cast(float, w & 0xFFFF0000u);
}
__device__ __forceinline__ float bfu(ushort_t h) {
    return __builtin_bit_cast(float, (unsigned)h << 16);
}

// ---------------------------------------------------------------------------
// One-time weight conversion: w1|w2|wf -> bf16. Block 0 additionally zeroes
// the 1536-float raw-stats area (ws is poisoned between iterations; the
// GEMM epilogues atomically accumulate into it).
// ---------------------------------------------------------------------------
__global__ __launch_bounds__(256) void wcvt_k(
    const float* __restrict__ w1, const float* __restrict__ w2,
    const float* __restrict__ wf,
    ushort_t* __restrict__ wb1, ushort_t* __restrict__ wb2,
    ushort_t* __restrict__ wbf, float* __restrict__ st)
{
    const int mb = blockIdx.x >> 6;          // 0..2: which matrix
    const int i  = (blockIdx.x & 63) * 256 + threadIdx.x;   // float4 index
    if (blockIdx.x == 0) {
        #pragma unroll
        for (int k = 0; k < 6; ++k) st[k * 256 + threadIdx.x] = 0.f;
    }
    const float* src = (mb == 0) ? w1 : (mb == 1) ? w2 : wf;
    ushort_t*    dst = (mb == 0) ? wb1 : (mb == 1) ? wb2 : wbf;
    float4 v = ((const float4*)src)[i];
    uint2 p;
    p.x = pk_bf16(v.x, v.y);
    p.y = pk_bf16(v.z, v.w);
    ((uint2*)dst)[i] = p;
}

// ---------------------------------------------------------------------------
// Dual conv1x1 via bf16 MFMA, double-buffered (R4). NEW: epilogue computes
// per-channel partial (sum, sumsq) of acc+bias, 16-lane shfl-reduce, one
// global f32 atomicAdd per channel per stat -> kills bn_stats2_k dispatch.
// ---------------------------------------------------------------------------
__global__ __launch_bounds__(256, 3) void dual_gemm_k(
    const float* __restrict__ x,
    const ushort_t* __restrict__ wb1, const float* __restrict__ b1,
    const ushort_t* __restrict__ wb2, const float* __restrict__ b2,
    ushort_t* __restrict__ y1, ushort_t* __restrict__ y2,
    float* __restrict__ stS1, float* __restrict__ stQ1,
    float* __restrict__ stS2, float* __restrict__ stQ2)
{
    __shared__ short sA1[2][128 * KP];
    __shared__ short sA2[2][128 * KP];
    __shared__ short sB [2][64 * KP];

    const int tid = threadIdx.x;
    const int l0 = blockIdx.x * 64;
    const int o0 = blockIdx.y * 128;
    const int b  = blockIdx.z;

    const int wv = tid >> 6;
    const int lane = tid & 63;
    const int m = lane & 15;
    const int quad = lane >> 4;

    const float* xb = x + (size_t)b * CCH * L;

    const int sl = tid & 63, soct = tid >> 6;
    const int sr = tid & 127, sh = tid >> 7;

    f32x4 acc1[2][4], acc2[2][4];
    #pragma unroll
    for (int io = 0; io < 2; ++io)
        #pragma unroll
        for (int jl = 0; jl < 4; ++jl) {
            acc1[io][jl] = (f32x4){0.f,0.f,0.f,0.f};
            acc2[io][jl] = (f32x4){0.f,0.f,0.f,0.f};
        }

    float fx[8];
    uint4 pw1a, pw1b, pw2a, pw2b;

    auto LOADT = [&](int s) {
        const int k0 = s * 32;
        const float* xs = xb + (size_t)(k0 + soct * 8) * L + l0 + sl;
        #pragma unroll
        for (int j = 0; j < 8; ++j) fx[j] = xs[(size_t)j * L];
        const uint4* wp = (const uint4*)&wb1[(size_t)(o0 + sr) * CCH + k0 + sh * 16];
        pw1a = wp[0]; pw1b = wp[1];
        const uint4* wq = (const uint4*)&wb2[(size_t)(o0 + sr) * CCH + k0 + sh * 16];
        pw2a = wq[0]; pw2b = wq[1];
    };
    auto STORET = [&](int buf) {
        uint4 v;
        v.x = pk_bf16(fx[0], fx[1]);
        v.y = pk_bf16(fx[2], fx[3]);
        v.z = pk_bf16(fx[4], fx[5]);
        v.w = pk_bf16(fx[6], fx[7]);
        *(uint4*)&sB[buf][sl * KP + soct * 8] = v;
        *(uint4*)&sA1[buf][sr * KP + sh * 16]     = pw1a;
        *(uint4*)&sA1[buf][sr * KP + sh * 16 + 8] = pw1b;
        *(uint4*)&sA2[buf][sr * KP + sh * 16]     = pw2a;
        *(uint4*)&sA2[buf][sr * KP + sh * 16 + 8] = pw2b;
    };

    LOADT(0);
    STORET(0);
    __syncthreads();

    for (int s = 0; s < 8; ++s) {
        const int buf = s & 1;
        if (s < 7) LOADT(s + 1);

        short8 a1[2], a2[2], bfr[4];
        #pragma unroll
        for (int io = 0; io < 2; ++io) {
            a1[io] = *(const short8*)&sA1[buf][(wv * 32 + io * 16 + m) * KP + quad * 8];
            a2[io] = *(const short8*)&sA2[buf][(wv * 32 + io * 16 + m) * KP + quad * 8];
        }
        #pragma unroll
        for (int jl = 0; jl < 4; ++jl)
            bfr[jl] = *(const short8*)&sB[buf][(jl * 16 + m) * KP + quad * 8];
        #pragma unroll
        for (int io = 0; io < 2; ++io)
            #pragma unroll
            for (int jl = 0; jl < 4; ++jl) {
                acc1[io][jl] = __builtin_amdgcn_mfma_f32_16x16x32_bf16(a1[io], bfr[jl], acc1[io][jl], 0, 0, 0);
                acc2[io][jl] = __builtin_amdgcn_mfma_f32_16x16x32_bf16(a2[io], bfr[jl], acc2[io][jl], 0, 0, 0);
            }

        if (s < 7) STORET(buf ^ 1);
        __syncthreads();
    }

    #pragma unroll
    for (int io = 0; io < 2; ++io)
        #pragma unroll
        for (int reg = 0; reg < 4; ++reg) {
            const int o = o0 + wv * 32 + io * 16 + quad * 4 + reg;
            const float bb1 = b1[o], bb2 = b2[o];
            float v1[4], v2[4];
            #pragma unroll
            for (int jl = 0; jl < 4; ++jl) {
                v1[jl] = acc1[io][jl][reg] + bb1;
                v2[jl] = acc2[io][jl][reg] + bb2;
            }
            const size_t ro = ((size_t)b * CCH + o) * L + l0 + m;
            unsigned u1a = pk_bf16(v1[0], v1[1]);
            unsigned u1b = pk_bf16(v1[2], v1[3]);
            unsigned u2a = pk_bf16(v2[0], v2[1]);
            unsigned u2b = pk_bf16(v2[2], v2[3]);
            y1[ro]      = (ushort_t)u1a;
            y1[ro + 16] = (ushort_t)(u1a >> 16);
            y1[ro + 32] = (ushort_t)u1b;
            y1[ro + 48] = (ushort_t)(u1b >> 16);
            y2[ro]      = (ushort_t)u2a;
            y2[ro + 16] = (ushort_t)(u2a >> 16);
            y2[ro + 32] = (ushort_t)u2b;
            y2[ro + 48] = (ushort_t)(u2b >> 16);

            float s1 = (v1[0] + v1[1]) + (v1[2] + v1[3]);
            float q1 = (v1[0]*v1[0] + v1[1]*v1[1]) + (v1[2]*v1[2] + v1[3]*v1[3]);
            float s2 = (v2[0] + v2[1]) + (v2[2] + v2[3]);
            float q2 = (v2[0]*v2[0] + v2[1]*v2[1]) + (v2[2]*v2[2] + v2[3]*v2[3]);
            #pragma unroll
            for (int d = 1; d < 16; d <<= 1) {
                s1 += __shfl_xor(s1, d); q1 += __shfl_xor(q1, d);
                s2 += __shfl_xor(s2, d); q2 += __shfl_xor(q2, d);
            }
            if (m == 0) {
                atomicAdd(&stS1[o], s1); atomicAdd(&stQ1[o], q1);
                atomicAdd(&stS2[o], s2); atomicAdd(&stQ2[o], q2);
            }
        }
}

// ---------------------------------------------------------------------------
// Single conv1x1 via bf16 MFMA, double-buffered (R4). NEW: epilogue
// accumulates final-BN raw stats via atomics (bn_fused's reduce removed).
// ---------------------------------------------------------------------------
__global__ __launch_bounds__(256, 4) void single_gemm_k(
    const ushort_t* __restrict__ x,
    const ushort_t* __restrict__ wb, const float* __restrict__ bb,
    ushort_t* __restrict__ y,
    float* __restrict__ stS, float* __restrict__ stQ)
{
    __shared__ short sA[2][128 * KP];
    __shared__ short sB[2][64 * KP];

    const int tid = threadIdx.x;
    const int l0 = blockIdx.x * 64;
    const int o0 = blockIdx.y * 128;
    const int b  = blockIdx.z;

    const int wv = tid >> 6;
    const int lane = tid & 63;
    const int m = lane & 15;
    const int quad = lane >> 4;

    const ushort_t* xb = x + (size_t)b * CCH * L;

    const int sl = tid & 63, soct = tid >> 6;
    const int sr = tid & 127, sh = tid >> 7;

    f32x4 acc[2][4];
    #pragma unroll
    for (int io = 0; io < 2; ++io)
        #pragma unroll
        for (int jl = 0; jl < 4; ++jl)
            acc[io][jl] = (f32x4){0.f,0.f,0.f,0.f};

    ushort_t hx[8];
    uint4 pwa, pwb;

    auto LOADT = [&](int s) {
        const int k0 = s * 32;
        const ushort_t* xs = xb + (size_t)(k0 + soct * 8) * L + l0 + sl;
        #pragma unroll
        for (int j = 0; j < 8; ++j) hx[j] = xs[(size_t)j * L];
        const uint4* wp = (const uint4*)&wb[(size_t)(o0 + sr) * CCH + k0 + sh * 16];
        pwa = wp[0]; pwb = wp[1];
    };
    auto STORET = [&](int buf) {
        short8 v;
        #pragma unroll
        for (int j = 0; j < 8; ++j) v[j] = (short)hx[j];
        *(short8*)&sB[buf][sl * KP + soct * 8] = v;
        *(uint4*)&sA[buf][sr * KP + sh * 16]     = pwa;
        *(uint4*)&sA[buf][sr * KP + sh * 16 + 8] = pwb;
    };

    LOADT(0);
    STORET(0);
    __syncthreads();

    for (int s = 0; s < 8; ++s) {
        const int buf = s & 1;
        if (s < 7) LOADT(s + 1);

        short8 a[2], bfr[4];
        #pragma unroll
        for (int io = 0; io < 2; ++io)
            a[io] = *(const short8*)&sA[buf][(wv * 32 + io * 16 + m) * KP + quad * 8];
        #pragma unroll
        for (int jl = 0; jl < 4; ++jl)
            bfr[jl] = *(const short8*)&sB[buf][(jl * 16 + m) * KP + quad * 8];
        #pragma unroll
        for (int io = 0; io < 2; ++io)
            #pragma unroll
            for (int jl = 0; jl < 4; ++jl)
                acc[io][jl] = __builtin_amdgcn_mfma_f32_16x16x32_bf16(a[io], bfr[jl], acc[io][jl], 0, 0, 0);

        if (s < 7) STORET(buf ^ 1);
        __syncthreads();
    }

    #pragma unroll
    for (int io = 0; io < 2; ++io)
        #pragma unroll
        for (int reg = 0; reg < 4; ++reg) {
            const int o = o0 + wv * 32 + io * 16 + quad * 4 + reg;
            const float b0 = bb[o];
            float v[4];
            #pragma unroll
            for (int jl = 0; jl < 4; ++jl) v[jl] = acc[io][jl][reg] + b0;
            const size_t ro = ((size_t)b * CCH + o) * L + l0 + m;
            unsigned ua = pk_bf16(v[0], v[1]);
            unsigned ub = pk_bf16(v[2], v[3]);
            y[ro]      = (ushort_t)ua;
            y[ro + 16] = (ushort_t)(ua >> 16);
            y[ro + 32] = (ushort_t)ub;
            y[ro + 48] = (ushort_t)(ub >> 16);

            float s0 = (v[0] + v[1]) + (v[2] + v[3]);
            float q0 = (v[0]*v[0] + v[1]*v[1]) + (v[2]*v[2] + v[3]*v[3]);
            #pragma unroll
            for (int d = 1; d < 16; d <<= 1) {
                s0 += __shfl_xor(s0, d); q0 += __shfl_xor(q0, d);
            }
            if (m == 0) {
                atomicAdd(&stS[o], s0); atomicAdd(&stQ[o], q0);
            }
        }
}

// ---------------------------------------------------------------------------
// Attention (R3 fused version — verified). NEW: finalizes BN scale/shift
// in-prologue from the raw atomic sums (log2e folded for the K tensor).
// No LDS atomics (R1 lesson: CAS loop serializes 4x); race-free phased RMW.
// ---------------------------------------------------------------------------
__global__ __launch_bounds__(512, 6) void attention_k(
    const float* __restrict__ x,
    const ushort_t* __restrict__ y1,
    const ushort_t* __restrict__ y2,
    const float* __restrict__ stS1, const float* __restrict__ stQ1,
    const float* __restrict__ stS2, const float* __restrict__ stQ2,
    const float* __restrict__ g1, const float* __restrict__ be1,
    const float* __restrict__ g2, const float* __restrict__ be2,
    ushort_t* __restrict__ pre)
{
    __shared__ unsigned sKQg[4240];   // [GOF+s] = packed bf16 (k', q); guards zero
    __shared__ ushort_t sXg [4240];   // [GOF+s] = bf16 x; guards zero
    __shared__ float    accF[L];      // output accumulator (16 KB)

    const int bc = blockIdx.x;
    const int tid = threadIdx.x;
    const int ch = bc & 255;
    const size_t off = (size_t)bc * L;

    // finalize BN params from raw sums (broadcast loads, ~20 VALU)
    float sc1, sh1, sc2, sh2;
    {
        float S = stS1[ch], Q = stQ1[ch];
        float mean = S * INVN, var = Q * INVN - mean * mean;
        float rstd = rsqrtf(var + 1e-5f);
        float g = g1[ch];
        sc1 = LOG2E * g * rstd;
        sh1 = LOG2E * (be1[ch] - mean * g * rstd);
        S = stS2[ch]; Q = stQ2[ch];
        mean = S * INVN; var = Q * INVN - mean * mean;
        rstd = rsqrtf(var + 1e-5f);
        g = g2[ch];
        sc2 = g * rstd;
        sh2 = be2[ch] - mean * g * rstd;
    }

    // ---- stage + guards + zero accumulator ---------------------------
    if (tid < GOF)  { sKQg[tid] = 0; sXg[tid] = 0; }
    if (tid < 72)   { sKQg[GOF + 4096 + tid] = 0; sXg[GOF + 4096 + tid] = 0; }
    {
        float4 z = {0.f, 0.f, 0.f, 0.f};
        ((float4*)accF)[tid]       = z;
        ((float4*)accF)[tid + 512] = z;
    }
    {
        uint4 ak = ((const uint4*)(y1 + off))[tid];
        uint4 aq = ((const uint4*)(y2 + off))[tid];
        float4 xa = ((const float4*)(x + off))[2 * tid];
        float4 xb = ((const float4*)(x + off))[2 * tid + 1];
        unsigned wk[4] = {ak.x, ak.y, ak.z, ak.w};
        unsigned wq[4] = {aq.x, aq.y, aq.z, aq.w};
        unsigned kq[8];
        #pragma unroll
        for (int u = 0; u < 4; ++u) {
            float klo = fmaxf(fmaf(bflo(wk[u]), sc1, sh1), 0.f);
            float khi = fmaxf(fmaf(bfhi(wk[u]), sc1, sh1), 0.f);
            float qlo = fmaxf(fmaf(bflo(wq[u]), sc2, sh2), 0.f);
            float qhi = fmaxf(fmaf(bfhi(wq[u]), sc2, sh2), 0.f);
            kq[2*u]   = (unsigned)f2bf(klo) | ((unsigned)f2bf(qlo) << 16);
            kq[2*u+1] = (unsigned)f2bf(khi) | ((unsigned)f2bf(qhi) << 16);
        }
        *(uint4*)&sKQg[GOF + 8 * tid]     = make_uint4(kq[0], kq[1], kq[2], kq[3]);
        *(uint4*)&sKQg[GOF + 8 * tid + 4] = make_uint4(kq[4], kq[5], kq[6], kq[7]);
        float xv[8] = {xa.x, xa.y, xa.z, xa.w, xb.x, xb.y, xb.z, xb.w};
        unsigned xp[4];
        #pragma unroll
        for (int u = 0; u < 4; ++u)
            xp[u] = (unsigned)f2bf(xv[2*u]) | ((unsigned)f2bf(xv[2*u+1]) << 16);
        *(uint4*)&sXg[GOF + 8 * tid] = make_uint4(xp[0], xp[1], xp[2], xp[3]);
    }
    __syncthreads();

    // ---- fused per-window softmax + phased scatter-accumulate ---------
    {
        const int fbase = 9 * tid;
        #pragma unroll
        for (int r = 0; r < 8; ++r) {
            const int f  = fbase + 4608 * r;       // f = 9 * window_index
            const int t  = f >> 12;
            const int fl = f & 4095;
            unsigned wv[9];
            float    xw[9];
            const bool fastp = (fl < 4088);
            if (fastp) {                           // fast path: single tap t
                const int di = (t * 86) >> 8;
                const int dj = t - 3 * di;
                const int cbad = (dj == 0) ? 0 : ((dj == 2) ? 63 : 99);
                const int base = fl + (di << 6) + dj - 65 + GOF;
                #pragma unroll
                for (int j = 0; j < 9; ++j) {
                    wv[j] = sKQg[base + j];
                    xw[j] = bfu(sXg[base + j]);
                }
                #pragma unroll
                for (int j = 0; j < 9; ++j) {
                    int c = (fl + j) & 63;
                    bool bad = (c == cbad);
                    wv[j] = bad ? 0u  : wv[j];
                    xw[j] = bad ? 0.f : xw[j];
                }
            } else {                               // straddle: generic decode
                #pragma unroll
                for (int j = 0; j < 9; ++j) {
                    int fj = f + j;
                    int tj = fj >> 12, lj = fj & 4095;
                    int dij = (tj * 86) >> 8, djj = tj - 3 * dij;
                    int idx = lj + (dij << 6) + djj - 65 + GOF;
                    unsigned wr = sKQg[idx];
                    float    xr = bfu(sXg[idx]);
                    int c = lj & 63;
                    int cb = (djj == 0) ? 0 : ((djj == 2) ? 63 : 99);
                    bool bad = (c == cb);
                    wv[j] = bad ? 0u  : wr;
                    xw[j] = bad ? 0.f : xr;
                }
            }
            const unsigned cw = wv[4];
            const float kc = bflo(cw), qc = bfhi(cw);
            float e[9];
            #pragma unroll
            for (int j = 0; j < 9; ++j)
                e[j] = __builtin_amdgcn_exp2f(bflo(wv[j]) * qc + kc * bfhi(wv[j]));
            float s = (((e[0] + e[1]) + (e[2] + e[3])) +
                       ((e[4] + e[5]) + (e[6] + e[7]))) + e[8];
            const float rinv = __builtin_amdgcn_rcpf(s);
            float cj[9];
            #pragma unroll
            for (int j = 0; j < 9; ++j)
                cj[j] = e[j] * rinv * xw[j];

            // phased race-free RMW (collisions only at dtid in {455,456})
            __syncthreads();
            if (tid < 455) {
                if (fastp) {
                    #pragma unroll
                    for (int j = 0; j < 9; ++j) accF[fl + j] += cj[j];
                } else {
                    #pragma unroll
                    for (int j = 0; j < 9; ++j) accF[(f + j) & 4095] += cj[j];
                }
            }
            __syncthreads();
            if (tid >= 455) {
                if (fastp) {
                    #pragma unroll
                    for (int j = 0; j < 9; ++j) accF[fl + j] += cj[j];
                } else {
                    #pragma unroll
                    for (int j = 0; j < 9; ++j) accF[(f + j) & 4095] += cj[j];
                }
            }
        }
    }
    __syncthreads();

    // ---- write out (pairs -> 4B/lane coalesced stores) ----------------
    {
        unsigned* po = (unsigned*)(pre + off);
        #pragma unroll
        for (int rr = 0; rr < 4; ++rr) {
            const int p = rr * 512 + tid;
            po[p] = pk_bf16(accF[2 * p], accF[2 * p + 1]);
        }
    }
}

// ---------------------------------------------------------------------------
// Final BN apply + ReLU (stats precomputed by single_gemm atomics).
// Pure streaming: grid 1024 = (batch, channel), no LDS, no reduce.
// ---------------------------------------------------------------------------
__global__ __launch_bounds__(256) void bn_apply_k(
    const ushort_t* __restrict__ yf,
    const float* __restrict__ stS, const float* __restrict__ stQ,
    const float* __restrict__ gf, const float* __restrict__ bef,
    float* __restrict__ out)
{
    const int c = blockIdx.x & 255;
    const int b = blockIdx.x >> 8;
    const int tid = threadIdx.x;

    float S = stS[c], Q = stQ[c];
    float mean = S * INVN, var = Q * INVN - mean * mean;
    float rstd = rsqrtf(var + 1e-5f);
    float g = gf[c];
    const float sc = g * rstd;
    const float sh = bef[c] - mean * g * rstd;

    const uint4* p = (const uint4*)(yf + ((size_t)b * CCH + c) * L);
    float4* o = (float4*)(out + ((size_t)b * CCH + c) * L);
    #pragma unroll
    for (int r = 0; r < 2; ++r) {
        uint4 v = p[r * 256 + tid];
        unsigned w[4] = {v.x, v.y, v.z, v.w};
        float4 o0, o1;
        o0.x = fmaxf(fmaf(bflo(w[0]), sc, sh), 0.f);
        o0.y = fmaxf(fmaf(bfhi(w[0]), sc, sh), 0.f);
        o0.z = fmaxf(fmaf(bflo(w[1]), sc, sh), 0.f);
        o0.w = fmaxf(fmaf(bfhi(w[1]), sc, sh), 0.f);
        o1.x = fmaxf(fmaf(bflo(w[2]), sc, sh), 0.f);
        o1.y = fmaxf(fmaf(bfhi(w[2]), sc, sh), 0.f);
        o1.z = fmaxf(fmaf(bflo(w[3]), sc, sh), 0.f);
        o1.w = fmaxf(fmaf(bfhi(w[3]), sc, sh), 0.f);
        int i = r * 256 + tid;
        o[2 * i]     = o0;
        o[2 * i + 1] = o1;
    }
}

// ---------------------------------------------------------------------------
extern "C" void kernel_launch(void* const* d_in, const int* in_sizes, int n_in,
                              void* d_out, int out_size, void* d_ws, size_t ws_size,
                              hipStream_t stream) {
    const float* x   = (const float*)d_in[0];
    const float* w1  = (const float*)d_in[1];
    const float* b1  = (const float*)d_in[2];
    const float* g1  = (const float*)d_in[3];
    const float* be1 = (const float*)d_in[4];
    const float* w2  = (const float*)d_in[5];
    const float* b2  = (const float*)d_in[6];
    const float* g2  = (const float*)d_in[7];
    const float* be2 = (const float*)d_in[8];
    const float* wf  = (const float*)d_in[9];
    const float* bf  = (const float*)d_in[10];
    const float* gf  = (const float*)d_in[11];
    const float* bef = (const float*)d_in[12];
    float* out = (float*)d_out;

    const size_t NEL = (size_t)NB * CCH * L;       // 4194304
    ushort_t* y1b = (ushort_t*)d_ws;               // conv1 out (bf16); later yf
    ushort_t* y2b = y1b + NEL;                     // conv2 out (bf16); later pre
    float* st = (float*)(y2b + NEL);               // raw stats: 6 x 256
    float* stS1 = st,        *stQ1 = st + 256;
    float* stS2 = st + 512,  *stQ2 = st + 768;
    float* stSF = st + 1024, *stQF = st + 1280;
    ushort_t* wb1 = (ushort_t*)(st + 1536);        // bf16 weights: 3 x 64K
    ushort_t* wb2 = wb1 + CCH * CCH;
    ushort_t* wbf = wb2 + CCH * CCH;

    wcvt_k<<<192, 256, 0, stream>>>(w1, w2, wf, wb1, wb2, wbf, st);
    dim3 gg(64, 2, 4);
    dual_gemm_k<<<gg, 256, 0, stream>>>(x, wb1, b1, wb2, b2, y1b, y2b,
                                        stS1, stQ1, stS2, stQ2);
    attention_k<<<NB * CCH, 512, 0, stream>>>(x, y1b, y2b,
                                              stS1, stQ1, stS2, stQ2,
                                              g1, be1, g2, be2,
                                              /*pre=*/y2b);
    single_gemm_k<<<gg, 256, 0, stream>>>(/*pre=*/y2b, wbf, bf, /*yf=*/y1b,
                                          stSF, stQF);
    bn_apply_k<<<NB * CCH, 256, 0, stream>>>(y1b, stSF, stQF, gf, bef, out);
}

// Round 6
// 162.405 us; speedup vs baseline: 1.2459x; 1.2459x over previous
//
#include <hip/hip_runtime.h>
#include <hip/hip_bf16.h>

#define L 4096
#define CCH 256
#define NB 4
#define KP 40   // padded LDS row length (32 k + 8 pad) in bf16 elems; 80 B rows
#define GOF 72  // guarded-image front offset (alignment-friendly, >= 65)
#define LOG2E 1.4426950408889634f
#define INVN (1.0f / (NB * (float)L))
#define NPART 256   // stats partials per channel: 64 l-tiles x 4 batches

typedef __attribute__((ext_vector_type(8))) short short8;
typedef __attribute__((ext_vector_type(4))) float f32x4;
typedef unsigned short ushort_t;

__device__ __forceinline__ unsigned short f2bf(float f) {
    unsigned u = __builtin_bit_cast(unsigned, f);
    u += 0x7FFF + ((u >> 16) & 1);
    return (unsigned short)(u >> 16);
}
__device__ __forceinline__ unsigned pk_bf16(float a, float b) {
    __hip_bfloat162 h = __float22bfloat162_rn(make_float2(a, b));
    unsigned u;
    __builtin_memcpy(&u, &h, 4);
    return u;
}
__device__ __forceinline__ float bflo(unsigned w) {
    return __builtin_bit_cast(float, w << 16);
}
__device__ __forceinline__ float bfhi(unsigned w) {
    return __builtin_bit_cast(float, w & 0xFFFF0000u);
}
__device__ __forceinline__ float bfu(ushort_t h) {
    return __builtin_bit_cast(float, (unsigned)h << 16);
}

// ---------------------------------------------------------------------------
// One-time weight conversion: w1|w2|wf (each 256x256 f32) -> bf16
// ---------------------------------------------------------------------------
__global__ __launch_bounds__(256) void wcvt_k(
    const float* __restrict__ w1, const float* __restrict__ w2,
    const float* __restrict__ wf,
    ushort_t* __restrict__ wb1, ushort_t* __restrict__ wb2,
    ushort_t* __restrict__ wbf)
{
    const int mb = blockIdx.x >> 6;          // 0..2: which matrix
    const int i  = (blockIdx.x & 63) * 256 + threadIdx.x;   // float4 index
    const float* src = (mb == 0) ? w1 : (mb == 1) ? w2 : wf;
    ushort_t*    dst = (mb == 0) ? wb1 : (mb == 1) ? wb2 : wbf;
    float4 v = ((const float4*)src)[i];
    uint2 p;
    p.x = pk_bf16(v.x, v.y);
    p.y = pk_bf16(v.z, v.w);
    ((uint2*)dst)[i] = p;
}

// ---------------------------------------------------------------------------
// Dual conv1x1 via bf16 MFMA, double-buffered. Epilogue: per-channel partial
// (sum, sumsq) -> PLAIN STORE to a unique slot stP[o*NPART + b*64 + bx].
// NO fp atomics anywhere (R5 lesson: atomicAdd(float*) on global = CAS loop
// under contention, +30 us tail; R1: same for LDS).
// ---------------------------------------------------------------------------
__global__ __launch_bounds__(256, 3) void dual_gemm_k(
    const float* __restrict__ x,
    const ushort_t* __restrict__ wb1, const float* __restrict__ b1,
    const ushort_t* __restrict__ wb2, const float* __restrict__ b2,
    ushort_t* __restrict__ y1, ushort_t* __restrict__ y2,
    float* __restrict__ stPS1, float* __restrict__ stPQ1,
    float* __restrict__ stPS2, float* __restrict__ stPQ2)
{
    __shared__ short sA1[2][128 * KP];
    __shared__ short sA2[2][128 * KP];
    __shared__ short sB [2][64 * KP];

    const int tid = threadIdx.x;
    const int l0 = blockIdx.x * 64;
    const int o0 = blockIdx.y * 128;
    const int b  = blockIdx.z;
    const int part = b * 64 + blockIdx.x;

    const int wv = tid >> 6;
    const int lane = tid & 63;
    const int m = lane & 15;
    const int quad = lane >> 4;

    const float* xb = x + (size_t)b * CCH * L;

    const int sl = tid & 63, soct = tid >> 6;
    const int sr = tid & 127, sh = tid >> 7;

    f32x4 acc1[2][4], acc2[2][4];
    #pragma unroll
    for (int io = 0; io < 2; ++io)
        #pragma unroll
        for (int jl = 0; jl < 4; ++jl) {
            acc1[io][jl] = (f32x4){0.f,0.f,0.f,0.f};
            acc2[io][jl] = (f32x4){0.f,0.f,0.f,0.f};
        }

    float fx[8];
    uint4 pw1a, pw1b, pw2a, pw2b;

    auto LOADT = [&](int s) {
        const int k0 = s * 32;
        const float* xs = xb + (size_t)(k0 + soct * 8) * L + l0 + sl;
        #pragma unroll
        for (int j = 0; j < 8; ++j) fx[j] = xs[(size_t)j * L];
        const uint4* wp = (const uint4*)&wb1[(size_t)(o0 + sr) * CCH + k0 + sh * 16];
        pw1a = wp[0]; pw1b = wp[1];
        const uint4* wq = (const uint4*)&wb2[(size_t)(o0 + sr) * CCH + k0 + sh * 16];
        pw2a = wq[0]; pw2b = wq[1];
    };
    auto STORET = [&](int buf) {
        uint4 v;
        v.x = pk_bf16(fx[0], fx[1]);
        v.y = pk_bf16(fx[2], fx[3]);
        v.z = pk_bf16(fx[4], fx[5]);
        v.w = pk_bf16(fx[6], fx[7]);
        *(uint4*)&sB[buf][sl * KP + soct * 8] = v;
        *(uint4*)&sA1[buf][sr * KP + sh * 16]     = pw1a;
        *(uint4*)&sA1[buf][sr * KP + sh * 16 + 8] = pw1b;
        *(uint4*)&sA2[buf][sr * KP + sh * 16]     = pw2a;
        *(uint4*)&sA2[buf][sr * KP + sh * 16 + 8] = pw2b;
    };

    LOADT(0);
    STORET(0);
    __syncthreads();

    for (int s = 0; s < 8; ++s) {
        const int buf = s & 1;
        if (s < 7) LOADT(s + 1);

        short8 a1[2], a2[2], bfr[4];
        #pragma unroll
        for (int io = 0; io < 2; ++io) {
            a1[io] = *(const short8*)&sA1[buf][(wv * 32 + io * 16 + m) * KP + quad * 8];
            a2[io] = *(const short8*)&sA2[buf][(wv * 32 + io * 16 + m) * KP + quad * 8];
        }
        #pragma unroll
        for (int jl = 0; jl < 4; ++jl)
            bfr[jl] = *(const short8*)&sB[buf][(jl * 16 + m) * KP + quad * 8];
        #pragma unroll
        for (int io = 0; io < 2; ++io)
            #pragma unroll
            for (int jl = 0; jl < 4; ++jl) {
                acc1[io][jl] = __builtin_amdgcn_mfma_f32_16x16x32_bf16(a1[io], bfr[jl], acc1[io][jl], 0, 0, 0);
                acc2[io][jl] = __builtin_amdgcn_mfma_f32_16x16x32_bf16(a2[io], bfr[jl], acc2[io][jl], 0, 0, 0);
            }

        if (s < 7) STORET(buf ^ 1);
        __syncthreads();
    }

    #pragma unroll
    for (int io = 0; io < 2; ++io)
        #pragma unroll
        for (int reg = 0; reg < 4; ++reg) {
            const int o = o0 + wv * 32 + io * 16 + quad * 4 + reg;
            const float bb1 = b1[o], bb2 = b2[o];
            float v1[4], v2[4];
            #pragma unroll
            for (int jl = 0; jl < 4; ++jl) {
                v1[jl] = acc1[io][jl][reg] + bb1;
                v2[jl] = acc2[io][jl][reg] + bb2;
            }
            const size_t ro = ((size_t)b * CCH + o) * L + l0 + m;
            unsigned u1a = pk_bf16(v1[0], v1[1]);
            unsigned u1b = pk_bf16(v1[2], v1[3]);
            unsigned u2a = pk_bf16(v2[0], v2[1]);
            unsigned u2b = pk_bf16(v2[2], v2[3]);
            y1[ro]      = (ushort_t)u1a;
            y1[ro + 16] = (ushort_t)(u1a >> 16);
            y1[ro + 32] = (ushort_t)u1b;
            y1[ro + 48] = (ushort_t)(u1b >> 16);
            y2[ro]      = (ushort_t)u2a;
            y2[ro + 16] = (ushort_t)(u2a >> 16);
            y2[ro + 32] = (ushort_t)u2b;
            y2[ro + 48] = (ushort_t)(u2b >> 16);

            float s1 = (v1[0] + v1[1]) + (v1[2] + v1[3]);
            float q1 = (v1[0]*v1[0] + v1[1]*v1[1]) + (v1[2]*v1[2] + v1[3]*v1[3]);
            float s2 = (v2[0] + v2[1]) + (v2[2] + v2[3]);
            float q2 = (v2[0]*v2[0] + v2[1]*v2[1]) + (v2[2]*v2[2] + v2[3]*v2[3]);
            #pragma unroll
            for (int d = 1; d < 16; d <<= 1) {
                s1 += __shfl_xor(s1, d); q1 += __shfl_xor(q1, d);
                s2 += __shfl_xor(s2, d); q2 += __shfl_xor(q2, d);
            }
            if (m == 0) {
                stPS1[o * NPART + part] = s1; stPQ1[o * NPART + part] = q1;
                stPS2[o * NPART + part] = s2; stPQ2[o * NPART + part] = q2;
            }
        }
}

// ---------------------------------------------------------------------------
// Single conv1x1 via bf16 MFMA, double-buffered. Same partial-store epilogue.
// ---------------------------------------------------------------------------
__global__ __launch_bounds__(256, 4) void single_gemm_k(
    const ushort_t* __restrict__ x,
    const ushort_t* __restrict__ wb, const float* __restrict__ bb,
    ushort_t* __restrict__ y,
    float* __restrict__ stPS, float* __restrict__ stPQ)
{
    __shared__ short sA[2][128 * KP];
    __shared__ short sB[2][64 * KP];

    const int tid = threadIdx.x;
    const int l0 = blockIdx.x * 64;
    const int o0 = blockIdx.y * 128;
    const int b  = blockIdx.z;
    const int part = b * 64 + blockIdx.x;

    const int wv = tid >> 6;
    const int lane = tid & 63;
    const int m = lane & 15;
    const int quad = lane >> 4;

    const ushort_t* xb = x + (size_t)b * CCH * L;

    const int sl = tid & 63, soct = tid >> 6;
    const int sr = tid & 127, sh = tid >> 7;

    f32x4 acc[2][4];
    #pragma unroll
    for (int io = 0; io < 2; ++io)
        #pragma unroll
        for (int jl = 0; jl < 4; ++jl)
            acc[io][jl] = (f32x4){0.f,0.f,0.f,0.f};

    ushort_t hx[8];
    uint4 pwa, pwb;

    auto LOADT = [&](int s) {
        const int k0 = s * 32;
        const ushort_t* xs = xb + (size_t)(k0 + soct * 8) * L + l0 + sl;
        #pragma unroll
        for (int j = 0; j < 8; ++j) hx[j] = xs[(size_t)j * L];
        const uint4* wp = (const uint4*)&wb[(size_t)(o0 + sr) * CCH + k0 + sh * 16];
        pwa = wp[0]; pwb = wp[1];
    };
    auto STORET = [&](int buf) {
        short8 v;
        #pragma unroll
        for (int j = 0; j < 8; ++j) v[j] = (short)hx[j];
        *(short8*)&sB[buf][sl * KP + soct * 8] = v;
        *(uint4*)&sA[buf][sr * KP + sh * 16]     = pwa;
        *(uint4*)&sA[buf][sr * KP + sh * 16 + 8] = pwb;
    };

    LOADT(0);
    STORET(0);
    __syncthreads();

    for (int s = 0; s < 8; ++s) {
        const int buf = s & 1;
        if (s < 7) LOADT(s + 1);

        short8 a[2], bfr[4];
        #pragma unroll
        for (int io = 0; io < 2; ++io)
            a[io] = *(const short8*)&sA[buf][(wv * 32 + io * 16 + m) * KP + quad * 8];
        #pragma unroll
        for (int jl = 0; jl < 4; ++jl)
            bfr[jl] = *(const short8*)&sB[buf][(jl * 16 + m) * KP + quad * 8];
        #pragma unroll
        for (int io = 0; io < 2; ++io)
            #pragma unroll
            for (int jl = 0; jl < 4; ++jl)
                acc[io][jl] = __builtin_amdgcn_mfma_f32_16x16x32_bf16(a[io], bfr[jl], acc[io][jl], 0, 0, 0);

        if (s < 7) STORET(buf ^ 1);
        __syncthreads();
    }

    #pragma unroll
    for (int io = 0; io < 2; ++io)
        #pragma unroll
        for (int reg = 0; reg < 4; ++reg) {
            const int o = o0 + wv * 32 + io * 16 + quad * 4 + reg;
            const float b0 = bb[o];
            float v[4];
            #pragma unroll
            for (int jl = 0; jl < 4; ++jl) v[jl] = acc[io][jl][reg] + b0;
            const size_t ro = ((size_t)b * CCH + o) * L + l0 + m;
            unsigned ua = pk_bf16(v[0], v[1]);
            unsigned ub = pk_bf16(v[2], v[3]);
            y[ro]      = (ushort_t)ua;
            y[ro + 16] = (ushort_t)(ua >> 16);
            y[ro + 32] = (ushort_t)ub;
            y[ro + 48] = (ushort_t)(ub >> 16);

            float s0 = (v[0] + v[1]) + (v[2] + v[3]);
            float q0 = (v[0]*v[0] + v[1]*v[1]) + (v[2]*v[2] + v[3]*v[3]);
            #pragma unroll
            for (int d = 1; d < 16; d <<= 1) {
                s0 += __shfl_xor(s0, d); q0 += __shfl_xor(q0, d);
            }
            if (m == 0) {
                stPS[o * NPART + part] = s0; stPQ[o * NPART + part] = q0;
            }
        }
}

// ---------------------------------------------------------------------------
// Attention (R3 fused version — verified). Prologue: reduce the 256 stats
// partials per tensor (waves 0-3: tensor1, waves 4-7: tensor2), finalize BN
// scale/shift (log2e folded into tensor-1). Then fused softmax+scatter with
// race-free phased LDS RMW (no LDS atomics).
// ---------------------------------------------------------------------------
__global__ __launch_bounds__(512, 6) void attention_k(
    const float* __restrict__ x,
    const ushort_t* __restrict__ y1,
    const ushort_t* __restrict__ y2,
    const float* __restrict__ stPS1, const float* __restrict__ stPQ1,
    const float* __restrict__ stPS2, const float* __restrict__ stPQ2,
    const float* __restrict__ g1, const float* __restrict__ be1,
    const float* __restrict__ g2, const float* __restrict__ be2,
    ushort_t* __restrict__ pre)
{
    __shared__ unsigned sKQg[4240];   // [GOF+s] = packed bf16 (k', q); guards zero
    __shared__ ushort_t sXg [4240];   // [GOF+s] = bf16 x; guards zero
    __shared__ float    accF[L];      // output accumulator (16 KB)
    __shared__ float    redS[8], redQ[8], bnP[4];

    const int bc = blockIdx.x;
    const int tid = threadIdx.x;
    const int ch = bc & 255;
    const size_t off = (size_t)bc * L;
    const int wid = tid >> 6, lane = tid & 63;

    // ---- reduce stats partials + zero guards/accumulator --------------
    {
        const float* PS = (tid < 256) ? stPS1 : stPS2;
        const float* PQ = (tid < 256) ? stPQ1 : stPQ2;
        const int t = tid & 255;
        float s = PS[ch * NPART + t];
        float q = PQ[ch * NPART + t];
        #pragma unroll
        for (int d = 1; d < 64; d <<= 1) {
            s += __shfl_xor(s, d);
            q += __shfl_xor(q, d);
        }
        if (lane == 0) { redS[wid] = s; redQ[wid] = q; }
    }
    if (tid < GOF)  { sKQg[tid] = 0; sXg[tid] = 0; }
    if (tid < 72)   { sKQg[GOF + 4096 + tid] = 0; sXg[GOF + 4096 + tid] = 0; }
    {
        float4 z = {0.f, 0.f, 0.f, 0.f};
        ((float4*)accF)[tid]       = z;
        ((float4*)accF)[tid + 512] = z;
    }
    __syncthreads();
    if (tid == 0) {
        float S1 = (redS[0] + redS[1]) + (redS[2] + redS[3]);
        float Q1 = (redQ[0] + redQ[1]) + (redQ[2] + redQ[3]);
        float S2 = (redS[4] + redS[5]) + (redS[6] + redS[7]);
        float Q2 = (redQ[4] + redQ[5]) + (redQ[6] + redQ[7]);
        float mean = S1 * INVN, var = Q1 * INVN - mean * mean;
        float rstd = rsqrtf(var + 1e-5f);
        float g = g1[ch];
        bnP[0] = LOG2E * g * rstd;
        bnP[1] = LOG2E * (be1[ch] - mean * g * rstd);
        mean = S2 * INVN; var = Q2 * INVN - mean * mean;
        rstd = rsqrtf(var + 1e-5f);
        g = g2[ch];
        bnP[2] = g * rstd;
        bnP[3] = be2[ch] - mean * g * rstd;
    }
    __syncthreads();
    const float sc1 = bnP[0], sh1 = bnP[1];   // pre-scaled by log2e
    const float sc2 = bnP[2], sh2 = bnP[3];

    // ---- stage --------------------------------------------------------
    {
        uint4 ak = ((const uint4*)(y1 + off))[tid];
        uint4 aq = ((const uint4*)(y2 + off))[tid];
        float4 xa = ((const float4*)(x + off))[2 * tid];
        float4 xb = ((const float4*)(x + off))[2 * tid + 1];
        unsigned wk[4] = {ak.x, ak.y, ak.z, ak.w};
        unsigned wq[4] = {aq.x, aq.y, aq.z, aq.w};
        unsigned kq[8];
        #pragma unroll
        for (int u = 0; u < 4; ++u) {
            float klo = fmaxf(fmaf(bflo(wk[u]), sc1, sh1), 0.f);
            float khi = fmaxf(fmaf(bfhi(wk[u]), sc1, sh1), 0.f);
            float qlo = fmaxf(fmaf(bflo(wq[u]), sc2, sh2), 0.f);
            float qhi = fmaxf(fmaf(bfhi(wq[u]), sc2, sh2), 0.f);
            kq[2*u]   = (unsigned)f2bf(klo) | ((unsigned)f2bf(qlo) << 16);
            kq[2*u+1] = (unsigned)f2bf(khi) | ((unsigned)f2bf(qhi) << 16);
        }
        *(uint4*)&sKQg[GOF + 8 * tid]     = make_uint4(kq[0], kq[1], kq[2], kq[3]);
        *(uint4*)&sKQg[GOF + 8 * tid + 4] = make_uint4(kq[4], kq[5], kq[6], kq[7]);
        float xv[8] = {xa.x, xa.y, xa.z, xa.w, xb.x, xb.y, xb.z, xb.w};
        unsigned xp[4];
        #pragma unroll
        for (int u = 0; u < 4; ++u)
            xp[u] = (unsigned)f2bf(xv[2*u]) | ((unsigned)f2bf(xv[2*u+1]) << 16);
        *(uint4*)&sXg[GOF + 8 * tid] = make_uint4(xp[0], xp[1], xp[2], xp[3]);
    }
    __syncthreads();

    // ---- fused per-window softmax + phased scatter-accumulate ---------
    {
        const int fbase = 9 * tid;
        #pragma unroll
        for (int r = 0; r < 8; ++r) {
            const int f  = fbase + 4608 * r;       // f = 9 * window_index
            const int t  = f >> 12;
            const int fl = f & 4095;
            unsigned wv[9];
            float    xw[9];
            const bool fastp = (fl < 4088);
            if (fastp) {                           // fast path: single tap t
                const int di = (t * 86) >> 8;
                const int dj = t - 3 * di;
                const int cbad = (dj == 0) ? 0 : ((dj == 2) ? 63 : 99);
                const int base = fl + (di << 6) + dj - 65 + GOF;
                #pragma unroll
                for (int j = 0; j < 9; ++j) {
                    wv[j] = sKQg[base + j];
                    xw[j] = bfu(sXg[base + j]);
                }
                #pragma unroll
                for (int j = 0; j < 9; ++j) {
                    int c = (fl + j) & 63;
                    bool bad = (c == cbad);
                    wv[j] = bad ? 0u  : wv[j];
                    xw[j] = bad ? 0.f : xw[j];
                }
            } else {                               // straddle: generic decode
                #pragma unroll
                for (int j = 0; j < 9; ++j) {
                    int fj = f + j;
                    int tj = fj >> 12, lj = fj & 4095;
                    int dij = (tj * 86) >> 8, djj = tj - 3 * dij;
                    int idx = lj + (dij << 6) + djj - 65 + GOF;
                    unsigned wr = sKQg[idx];
                    float    xr = bfu(sXg[idx]);
                    int c = lj & 63;
                    int cb = (djj == 0) ? 0 : ((djj == 2) ? 63 : 99);
                    bool bad = (c == cb);
                    wv[j] = bad ? 0u  : wr;
                    xw[j] = bad ? 0.f : xr;
                }
            }
            const unsigned cw = wv[4];
            const float kc = bflo(cw), qc = bfhi(cw);
            float e[9];
            #pragma unroll
            for (int j = 0; j < 9; ++j)
                e[j] = __builtin_amdgcn_exp2f(bflo(wv[j]) * qc + kc * bfhi(wv[j]));
            float s = (((e[0] + e[1]) + (e[2] + e[3])) +
                       ((e[4] + e[5]) + (e[6] + e[7]))) + e[8];
            const float rinv = __builtin_amdgcn_rcpf(s);
            float cj[9];
            #pragma unroll
            for (int j = 0; j < 9; ++j)
                cj[j] = e[j] * rinv * xw[j];

            // phased race-free RMW (collisions only at dtid in {455,456})
            __syncthreads();
            if (tid < 455) {
                if (fastp) {
                    #pragma unroll
                    for (int j = 0; j < 9; ++j) accF[fl + j] += cj[j];
                } else {
                    #pragma unroll
                    for (int j = 0; j < 9; ++j) accF[(f + j) & 4095] += cj[j];
                }
            }
            __syncthreads();
            if (tid >= 455) {
                if (fastp) {
                    #pragma unroll
                    for (int j = 0; j < 9; ++j) accF[fl + j] += cj[j];
                } else {
                    #pragma unroll
                    for (int j = 0; j < 9; ++j) accF[(f + j) & 4095] += cj[j];
                }
            }
        }
    }
    __syncthreads();

    // ---- write out (pairs -> 4B/lane coalesced stores) ----------------
    {
        unsigned* po = (unsigned*)(pre + off);
        #pragma unroll
        for (int rr = 0; rr < 4; ++rr) {
            const int p = rr * 512 + tid;
            po[p] = pk_bf16(accF[2 * p], accF[2 * p + 1]);
        }
    }
}

// ---------------------------------------------------------------------------
// Final BN apply + ReLU. Prologue reduces the 256 final-BN partials.
// Pure streaming: grid 1024 = (batch, channel), no big LDS.
// ---------------------------------------------------------------------------
__global__ __launch_bounds__(256) void bn_apply_k(
    const ushort_t* __restrict__ yf,
    const float* __restrict__ stPS, const float* __restrict__ stPQ,
    const float* __restrict__ gf, const float* __restrict__ bef,
    float* __restrict__ out)
{
    __shared__ float redS[4], redQ[4], bnP[2];

    const int c = blockIdx.x & 255;
    const int b = blockIdx.x >> 8;
    const int tid = threadIdx.x;
    const int wid = tid >> 6, lane = tid & 63;

    {
        float s = stPS[c * NPART + tid];
        float q = stPQ[c * NPART + tid];
        #pragma unroll
        for (int d = 1; d < 64; d <<= 1) {
            s += __shfl_xor(s, d);
            q += __shfl_xor(q, d);
        }
        if (lane == 0) { redS[wid] = s; redQ[wid] = q; }
    }
    __syncthreads();
    if (tid == 0) {
        float S = (redS[0] + redS[1]) + (redS[2] + redS[3]);
        float Q = (redQ[0] + redQ[1]) + (redQ[2] + redQ[3]);
        float mean = S * INVN, var = Q * INVN - mean * mean;
        float rstd = rsqrtf(var + 1e-5f);
        float g = gf[c];
        bnP[0] = g * rstd;
        bnP[1] = bef[c] - mean * g * rstd;
    }
    __syncthreads();
    const float sc = bnP[0], sh = bnP[1];

    const uint4* p = (const uint4*)(yf + ((size_t)b * CCH + c) * L);
    float4* o = (float4*)(out + ((size_t)b * CCH + c) * L);
    #pragma unroll
    for (int r = 0; r < 2; ++r) {
        uint4 v = p[r * 256 + tid];
        unsigned w[4] = {v.x, v.y, v.z, v.w};
        float4 o0, o1;
        o0.x = fmaxf(fmaf(bflo(w[0]), sc, sh), 0.f);
        o0.y = fmaxf(fmaf(bfhi(w[0]), sc, sh), 0.f);
        o0.z = fmaxf(fmaf(bflo(w[1]), sc, sh), 0.f);
        o0.w = fmaxf(fmaf(bfhi(w[1]), sc, sh), 0.f);
        o1.x = fmaxf(fmaf(bflo(w[2]), sc, sh), 0.f);
        o1.y = fmaxf(fmaf(bfhi(w[2]), sc, sh), 0.f);
        o1.z = fmaxf(fmaf(bflo(w[3]), sc, sh), 0.f);
        o1.w = fmaxf(fmaf(bfhi(w[3]), sc, sh), 0.f);
        int i = r * 256 + tid;
        o[2 * i]     = o0;
        o[2 * i + 1] = o1;
    }
}

// ---------------------------------------------------------------------------
extern "C" void kernel_launch(void* const* d_in, const int* in_sizes, int n_in,
                              void* d_out, int out_size, void* d_ws, size_t ws_size,
                              hipStream_t stream) {
    const float* x   = (const float*)d_in[0];
    const float* w1  = (const float*)d_in[1];
    const float* b1  = (const float*)d_in[2];
    const float* g1  = (const float*)d_in[3];
    const float* be1 = (const float*)d_in[4];
    const float* w2  = (const float*)d_in[5];
    const float* b2  = (const float*)d_in[6];
    const float* g2  = (const float*)d_in[7];
    const float* be2 = (const float*)d_in[8];
    const float* wf  = (const float*)d_in[9];
    const float* bf  = (const float*)d_in[10];
    const float* gf  = (const float*)d_in[11];
    const float* bef = (const float*)d_in[12];
    float* out = (float*)d_out;

    const size_t NEL = (size_t)NB * CCH * L;       // 4194304
    const size_t PSZ = (size_t)CCH * NPART;        // 65536 floats per array
    ushort_t* y1b = (ushort_t*)d_ws;               // conv1 out (bf16); later yf
    ushort_t* y2b = y1b + NEL;                     // conv2 out (bf16); later pre
    float* stP = (float*)(y2b + NEL);              // stats partials: 6 arrays
    float* stPS1 = stP,            *stPQ1 = stP + PSZ;
    float* stPS2 = stP + 2 * PSZ,  *stPQ2 = stP + 3 * PSZ;
    float* stPSF = stP + 4 * PSZ,  *stPQF = stP + 5 * PSZ;
    ushort_t* wb1 = (ushort_t*)(stP + 6 * PSZ);    // bf16 weights: 3 x 64K
    ushort_t* wb2 = wb1 + CCH * CCH;
    ushort_t* wbf = wb2 + CCH * CCH;

    wcvt_k<<<192, 256, 0, stream>>>(w1, w2, wf, wb1, wb2, wbf);
    dim3 gg(64, 2, 4);
    dual_gemm_k<<<gg, 256, 0, stream>>>(x, wb1, b1, wb2, b2, y1b, y2b,
                                        stPS1, stPQ1, stPS2, stPQ2);
    attention_k<<<NB * CCH, 512, 0, stream>>>(x, y1b, y2b,
                                              stPS1, stPQ1, stPS2, stPQ2,
                                              g1, be1, g2, be2,
                                              /*pre=*/y2b);
    single_gemm_k<<<gg, 256, 0, stream>>>(/*pre=*/y2b, wbf, bf, /*yf=*/y1b,
                                          stPSF, stPQF);
    bn_apply_k<<<NB * CCH, 256, 0, stream>>>(y1b, stPSF, stPQF, gf, bef, out);
}